// Round 2
// baseline (234.796 us; speedup 1.0000x reference)
//
#include <hip/hip_runtime.h>
#include <hip/hip_bf16.h>
#include <stdint.h>

#define T_ 2
#define N_ 4096
#define D_ 1024
#define E_ 8
#define O_ 1024

#define BM 128
#define BN 128
#define BK 32   // 64-B LDS rows

typedef __attribute__((ext_vector_type(8))) short short8;
typedef __attribute__((ext_vector_type(4))) float f32x4;

#define AS1 __attribute__((address_space(1)))
#define AS3 __attribute__((address_space(3)))

// async global->LDS, 16B per lane; LDS dest = base + lane*16 (wave-uniform base)
__device__ inline void gld16(const unsigned short* g, unsigned short* l) {
    __builtin_amdgcn_global_load_lds((const AS1 unsigned int*)g,
                                     (AS3 unsigned int*)l, 16, 0, 0);
}

__device__ inline unsigned short f2bf(float f) {
    union { float f; unsigned u; } v; v.f = f;
    unsigned r = v.u + 0x7fff + ((v.u >> 16) & 1);  // RNE
    return (unsigned short)(r >> 16);
}

// ---------------------------------------------------------------------------
// Kernel 1: gating + x->bf16. No atomics. 8 tokens/block, grid=1024.
// ---------------------------------------------------------------------------
__global__ __launch_bounds__(256) void gate_kernel(
    const float* __restrict__ x, const float* __restrict__ Wg,
    unsigned short* __restrict__ xb,
    int* __restrict__ route, float2* __restrict__ gpair)
{
    __shared__ __align__(16) float WgT[E_][D_];   // 32 KB

    int tid = threadIdx.x;
    int wave = tid >> 6, lane = tid & 63;
    int token0 = blockIdx.x * 8;
    int t = token0 >> 12;                 // 8 consecutive tokens share t
    const float* wgb = Wg + (size_t)t * D_ * E_;

#pragma unroll
    for (int r = 0; r < 8; ++r) {
        int f = r * 1024 + tid * 4;       // flat Wg index; (d=f>>3, e=f&7)
        float4 v = *(const float4*)(wgb + f);
        WgT[f & 7][f >> 3]             = v.x;
        WgT[(f + 1) & 7][(f + 1) >> 3] = v.y;
        WgT[(f + 2) & 7][(f + 2) >> 3] = v.z;
        WgT[(f + 3) & 7][(f + 3) >> 3] = v.w;
    }
    __syncthreads();

#pragma unroll
    for (int tl = 0; tl < 2; ++tl) {
        int token = token0 + wave * 2 + tl;
        const float* xrow = x + (size_t)token * D_;

        float4 xv[4];
#pragma unroll
        for (int c = 0; c < 4; ++c)
            xv[c] = *(const float4*)(xrow + c * 256 + lane * 4);

        float acc[E_] = {0.f, 0.f, 0.f, 0.f, 0.f, 0.f, 0.f, 0.f};
#pragma unroll
        for (int c = 0; c < 4; ++c) {
            int d0 = c * 256 + lane * 4;
            unsigned lo = f2bf(xv[c].x) | ((unsigned)f2bf(xv[c].y) << 16);
            unsigned hi = f2bf(xv[c].z) | ((unsigned)f2bf(xv[c].w) << 16);
            *(uint2*)(&xb[(size_t)token * D_ + d0]) = make_uint2(lo, hi);
#pragma unroll
            for (int e = 0; e < E_; ++e) {
                float4 w = *(const float4*)(&WgT[e][d0]);
                acc[e] += xv[c].x * w.x + xv[c].y * w.y + xv[c].z * w.z + xv[c].w * w.w;
            }
        }
#pragma unroll
        for (int off = 1; off < 64; off <<= 1) {
#pragma unroll
            for (int e = 0; e < E_; ++e) acc[e] += __shfl_xor(acc[e], off, 64);
        }

        if (lane == 0) {
            // top-2, lowest-index-first on ties (matches jax.lax.top_k)
            float best = acc[0]; int bi = 0;
#pragma unroll
            for (int e = 1; e < E_; ++e) if (acc[e] > best) { best = acc[e]; bi = e; }
            float sec = -INFINITY; int si = 0;
#pragma unroll
            for (int e = 0; e < E_; ++e) if (e != bi && acc[e] > sec) { sec = acc[e]; si = e; }
            float s = best + sec + 1e-9f;
            route[token] = bi | (si << 8);
            gpair[token] = make_float2(best / s, sec / s);
        }
    }
}

// ---------------------------------------------------------------------------
// Kernel 1b: deterministic stream compaction, one block per (t,e) group.
// 1024 threads: 4 serial chunk iterations instead of 16.
// toklist entry = n | (slot<<16); slot = 0 if e is token's primary expert.
// ---------------------------------------------------------------------------
__global__ __launch_bounds__(1024) void build_lists(
    const int* __restrict__ route, const float2* __restrict__ gpair,
    int* __restrict__ toklist, float* __restrict__ gatelist,
    int* __restrict__ counts)
{
    int g = blockIdx.x;              // t*8 + e
    int t = g >> 3, e = g & 7;
    int tid = threadIdx.x;
    int wave = tid >> 6, lane = tid & 63;

    __shared__ int waveSum[16];
    __shared__ int base;
    if (tid == 0) base = 0;

    for (int c = 0; c < N_; c += 1024) {
        int n = c + tid;
        int r = route[t * N_ + n];
        int e0 = r & 255, e1 = (r >> 8) & 255;
        bool sel = (e0 == e) || (e1 == e);
        unsigned long long b = __ballot(sel);
        int pre  = __popcll(b & ((1ull << lane) - 1ull));
        if (lane == 0) waveSum[wave] = __popcll(b);
        __syncthreads();
        int woff = 0, total = 0;
#pragma unroll
        for (int w = 0; w < 16; ++w) {
            int s = waveSum[w];
            total += s;
            woff += (w < wave) ? s : 0;
        }
        if (sel) {
            int p = base + woff + pre;
            int slot = (e0 == e) ? 0 : 1;
            toklist[g * N_ + p] = n | (slot << 16);
            float2 gp = gpair[t * N_ + n];
            gatelist[g * N_ + p] = (e0 == e) ? gp.x : gp.y;
        }
        __syncthreads();
        if (tid == 0) base += total;
    }
    __syncthreads();
    if (tid == 0) counts[g] = base;
}

// ---------------------------------------------------------------------------
// Kernel 2: We fp32 [e][d][o] -> bf16 packed [(e*8+o/128)*128 + o%128][d].
// ---------------------------------------------------------------------------
__global__ __launch_bounds__(256) void pack_kernel(
    const float* __restrict__ We, unsigned short* __restrict__ Wbp)
{
    __shared__ __align__(16) unsigned short P[64 * 136];

    int b = blockIdx.x;
    int e  = b >> 7;
    int oy = (b & 127) >> 3;   // 0..15
    int dz = b & 7;            // 0..7
    int o0 = oy * 64, d0 = dz * 128;
    int tid = threadIdx.x;

#pragma unroll
    for (int r = 0; r < 32; ++r) {
        int lin = r * 256 + tid;
        int dd = lin >> 6, oo = lin & 63;
        P[oo * 136 + dd] = f2bf(We[((size_t)(e * D_ + d0 + dd)) * O_ + o0 + oo]);
    }
    __syncthreads();

#pragma unroll
    for (int w = 0; w < 4; ++w) {
        int ci = w * 256 + tid;      // 1024 16B-chunks
        int oo = ci >> 4, dc = ci & 15;
        uint4 v = *(const uint4*)&P[oo * 136 + dc * 8];
        int o = o0 + oo;
        int ot = o >> 7, nn = o & 127;
        unsigned short* dst =
            Wbp + ((size_t)((e * 8 + ot) * 128 + nn)) * D_ + d0 + dc * 8;
        *(uint4*)dst = v;
    }
}

// ---------------------------------------------------------------------------
// Kernel 3: grouped GEMM, round 10: 128x256 effective tile (ot-PAIR).
// r9 post-mortem: conflicts 4.4M->0 and dbuf both landed per counters but
// dur unchanged -> latency-bound, per block-K-step wall ~1274cyc vs 310cyc
// MFMA work.  Fix = arithmetic intensity: each block computes its A-tile
// against TWO consecutive B tiles (ot = 2*ot2, 2*ot2+1 -> contiguous 256
// rows of Wbp).  Per wave/K-step: 12 ds_read -> 32 MFMA (was 8->16), acc
// 128 AGPR.  2 resident blocks/CU x 620cyc MFMA demand > chain latency ->
// MFMA pipe becomes the contended resource.
//  - 2-phase dbuf + quarter-phase-balanced swizzle kept from r9 (0 conflicts).
//  - mt-SLOWEST dispatch, xcd = lin%8; 64 (g,ot2) combos, grid 2048.
// ---------------------------------------------------------------------------
__global__ __launch_bounds__(256) void moe_gemm(
    const unsigned short* __restrict__ xb,   // [T*N][D] bf16
    const unsigned short* __restrict__ Wbp,  // [(e*8+ot)*128+n][D] bf16
    const int* __restrict__ toklist, const float* __restrict__ gatelist,
    const int* __restrict__ counts, float* __restrict__ out)
{
    int lin = blockIdx.x;            // 0..2047
    int mt  = lin >> 6;              // slowest: real tiles (mt < ~9) first
    int u   = lin & 63;
    int xcd = u & 7;                 // == lin % 8 == hw XCD round-robin
    int v   = u >> 3;                // 0..7
    int g   = 2 * xcd + (v >> 2);    // xcd owns groups {2x, 2x+1}
    int ot2 = v & 3;                 // B-tile pair: ot = 2*ot2, 2*ot2+1
    int t   = g >> 3;

    int cnt = counts[g];
    int m0 = mt * BM;
    if (m0 >= cnt) return;

    __shared__ __align__(16) unsigned short As[2][BM * BK];        // 16 KB
    __shared__ __align__(16) unsigned short Bs[2][2 * BN * BK];    // 32 KB
    __shared__ int   tokS[BM];
    __shared__ float gateS[BM];

    int tid = threadIdx.x;
    if (tid < BM) {
        int r = m0 + tid;
        tokS[tid]  = (r < cnt) ? toklist[g * N_ + r]  : -1;
        gateS[tid] = (r < cnt) ? gatelist[g * N_ + r] : 0.f;
    }
    __syncthreads();

    int wave = tid >> 6, lane = tid & 63;
    // staging: wave w stages A 16-row chunks {2w,2w+1}, B chunks {4w..4w+3}
    // (B = 256 contiguous Wbp rows for the ot-pair).  lane l -> row (l>>2)
    // of chunk, LDS granule (l&3); source granule sg = (l&3)^((l>>3)&3), so
    // LDS pos p of row r holds granule p^((r>>1)&3)  (chunk bases %16 == 0).
    int lr = lane >> 2;
    int sg = (lane & 3) ^ ((lane >> 3) & 3);
    int c0 = wave * 2, c1 = c0 + 1;
    int b0 = wave * 4;
    int ar0 = c0 * 16 + lr, ar1 = c1 * 16 + lr;
    int tok0 = max(tokS[ar0], 0) & 0xFFFF;   // junk rows masked in epilogue
    int tok1 = max(tokS[ar1], 0) & 0xFFFF;
    const unsigned short* ag0 = xb + ((size_t)(t * N_ + tok0)) * D_ + sg * 8;
    const unsigned short* ag1 = xb + ((size_t)(t * N_ + tok1)) * D_ + sg * 8;
    // 256 contiguous B rows: (e*8 + 2*ot2)*128 .. +255
    const unsigned short* wb  = Wbp + ((size_t)((g & 7) * 8 + ot2 * 2) * 128) * D_;
    const unsigned short* bg0 = wb + (size_t)((b0 + 0) * 16 + lr) * D_ + sg * 8;
    const unsigned short* bg1 = wb + (size_t)((b0 + 1) * 16 + lr) * D_ + sg * 8;
    const unsigned short* bg2 = wb + (size_t)((b0 + 2) * 16 + lr) * D_ + sg * 8;
    const unsigned short* bg3 = wb + (size_t)((b0 + 3) * 16 + lr) * D_ + sg * 8;

    int fr = lane & 15, q = lane >> 4;
    int wm = (wave & 1) * 64, wn = (wave >> 1) * 64;
    int fp = (q ^ ((fr >> 1) & 3)) * 8;      // read-side swizzled granule

    f32x4 acc[2][4][4];
#pragma unroll
    for (int tt = 0; tt < 2; ++tt)
#pragma unroll
        for (int mi = 0; mi < 4; ++mi)
#pragma unroll
            for (int ni = 0; ni < 4; ++ni) acc[tt][mi][ni] = (f32x4){0.f, 0.f, 0.f, 0.f};

    // prologue: stage K-tile 0 into buffer 0 (drained by first KSTEP's sync)
    gld16(ag0, &As[0][c0 * 512]);
    gld16(ag1, &As[0][c1 * 512]);
    gld16(bg0, &Bs[0][(b0 + 0) * 512]);
    gld16(bg1, &Bs[0][(b0 + 1) * 512]);
    gld16(bg2, &Bs[0][(b0 + 2) * 512]);
    gld16(bg3, &Bs[0][(b0 + 3) * 512]);

#define KSTEP(CUR, NXT, IT)                                                    \
    {                                                                          \
        __syncthreads(); /* publishes buf CUR (vmcnt0) + buf NXT read-done */  \
        int k1 = ((IT) + 1) * BK;                                              \
        if (k1 < D_) {                                                         \
            gld16(ag0 + k1, &As[NXT][c0 * 512]);                               \
            gld16(ag1 + k1, &As[NXT][c1 * 512]);                               \
            gld16(bg0 + k1, &Bs[NXT][(b0 + 0) * 512]);                         \
            gld16(bg1 + k1, &Bs[NXT][(b0 + 1) * 512]);                         \
            gld16(bg2 + k1, &Bs[NXT][(b0 + 2) * 512]);                         \
            gld16(bg3 + k1, &Bs[NXT][(b0 + 3) * 512]);                         \
        }                                                                      \
        short8 af[4], bf0[4], bf1[4];                                          \
        _Pragma("unroll") for (int mi = 0; mi < 4; ++mi)                       \
            af[mi] = *(const short8*)(&As[CUR][(wm + mi * 16 + fr) * BK + fp]);\
        _Pragma("unroll") for (int ni = 0; ni < 4; ++ni)                       \
            bf0[ni] = *(const short8*)(&Bs[CUR][(wn + ni * 16 + fr) * BK + fp]);\
        _Pragma("unroll") for (int ni = 0; ni < 4; ++ni)                       \
            bf1[ni] = *(const short8*)(&Bs[CUR][(128 + wn + ni * 16 + fr) * BK + fp]);\
        _Pragma("unroll") for (int mi = 0; mi < 4; ++mi)                       \
            _Pragma("unroll") for (int ni = 0; ni < 4; ++ni) {                 \
                acc[0][mi][ni] = __builtin_amdgcn_mfma_f32_16x16x32_bf16(      \
                    af[mi], bf0[ni], acc[0][mi][ni], 0, 0, 0);                 \
                acc[1][mi][ni] = __builtin_amdgcn_mfma_f32_16x16x32_bf16(      \
                    af[mi], bf1[ni], acc[1][mi][ni], 0, 0, 0);                 \
            }                                                                  \
    }

    for (int it = 0; it < D_ / BK; it += 2) {
        KSTEP(0, 1, it)
        KSTEP(1, 0, it + 1)
    }
#undef KSTEP

    // epilogue: C/D layout col = lane&15, row = q*4 + reg  [m89/m91]
    float* outb = out + (size_t)t * N_ * O_;
    int ncol = ot2 * 256 + wn + fr;
#pragma unroll
    for (int mi = 0; mi < 4; ++mi) {
#pragma unroll
        for (int r = 0; r < 4; ++r) {
            int ml = wm + mi * 16 + q * 4 + r;
            int ent = tokS[ml];
            if (ent >= 0) {
                int tok  = ent & 0xFFFF;
                int slot = ent >> 16;
                float gate = gateS[ml];
                float* orow = outb + (size_t)tok * O_;
#pragma unroll
                for (int tt = 0; tt < 2; ++tt) {
#pragma unroll
                    for (int ni = 0; ni < 4; ++ni) {
                        unsigned short* p =
                            (unsigned short*)(orow + ncol + tt * 128 + ni * 16);
                        p[slot] = f2bf(gate * acc[tt][mi][ni][r]);
                    }
                }
            }
        }
    }
}

// ---------------------------------------------------------------------------
// Kernel 4: combine the two bf16 slot halves of each out word into fp32.
// ---------------------------------------------------------------------------
__global__ __launch_bounds__(256) void combine_kernel(float* __restrict__ out)
{
    size_t i = ((size_t)blockIdx.x * 256 + threadIdx.x) * 4;
    unsigned* po = (unsigned*)out;
    uint4 v = *(uint4*)(po + i);
    float4 r;
    union { unsigned u; float f; } a, b;
#define CMB(comp, src) a.u = (src) << 16; b.u = (src) & 0xFFFF0000u; comp = a.f + b.f
    CMB(r.x, v.x); CMB(r.y, v.y); CMB(r.z, v.z); CMB(r.w, v.w);
#undef CMB
    *(float4*)(out + i) = r;
}

// ---------------------------------------------------------------------------
extern "C" void kernel_launch(void* const* d_in, const int* in_sizes, int n_in,
                              void* d_out, int out_size, void* d_ws, size_t ws_size,
                              hipStream_t stream)
{
    const float* x  = (const float*)d_in[0];
    const float* Wg = (const float*)d_in[1];
    const float* We = (const float*)d_in[2];
    float* out = (float*)d_out;

    char* ws = (char*)d_ws;
    unsigned short* xb   = (unsigned short*)(ws);               // 16,777,216 B
    unsigned short* Wbp  = (unsigned short*)(ws + 16777216);    // 16,777,216 B
    int*   toklist       = (int*)  (ws + 33554432);             //    262,144 B
    float* gatelist      = (float*)(ws + 33816576);             //    262,144 B
    int*   counts        = (int*)  (ws + 34078720);             //        256 B
    int*   route         = (int*)  (ws + 34078976);             //     32,768 B
    float2* gpair        = (float2*)(ws + 34111744);            //     65,536 B

    gate_kernel<<<(T_ * N_) / 8, 256, 0, stream>>>(x, Wg, xb, route, gpair);
    build_lists<<<T_ * E_, 1024, 0, stream>>>(route, gpair, toklist, gatelist, counts);
    pack_kernel<<<E_ * (O_ / 64) * (D_ / 128), 256, 0, stream>>>(We, Wbp);
    moe_gemm<<<(N_ / BM) * 16 * (T_ * E_) / 2, 256, 0, stream>>>(
        xb, Wbp, toklist, gatelist, counts, out);
    combine_kernel<<<((size_t)T_ * N_ * O_) / (256 * 4), 256, 0, stream>>>(out);
}

// Round 3
// 205.420 us; speedup vs baseline: 1.1430x; 1.1430x over previous
//
#include <hip/hip_runtime.h>
#include <hip/hip_bf16.h>
#include <stdint.h>

#define T_ 2
#define N_ 4096
#define D_ 1024
#define E_ 8
#define O_ 1024

#define BM 128
#define BN 128
#define BK 32   // 64-B LDS rows

typedef __attribute__((ext_vector_type(8))) short short8;
typedef __attribute__((ext_vector_type(4))) float f32x4;

#define AS1 __attribute__((address_space(1)))
#define AS3 __attribute__((address_space(3)))

// async global->LDS, 16B per lane; LDS dest = base + lane*16 (wave-uniform base)
__device__ inline void gld16(const unsigned short* g, unsigned short* l) {
    __builtin_amdgcn_global_load_lds((const AS1 unsigned int*)g,
                                     (AS3 unsigned int*)l, 16, 0, 0);
}

__device__ inline unsigned short f2bf(float f) {
    union { float f; unsigned u; } v; v.f = f;
    unsigned r = v.u + 0x7fff + ((v.u >> 16) & 1);  // RNE
    return (unsigned short)(r >> 16);
}

// ---------------------------------------------------------------------------
// Kernel 1: gating + x->bf16. No atomics. 8 tokens/block, grid=1024.
// ---------------------------------------------------------------------------
__global__ __launch_bounds__(256) void gate_kernel(
    const float* __restrict__ x, const float* __restrict__ Wg,
    unsigned short* __restrict__ xb,
    int* __restrict__ route, float2* __restrict__ gpair)
{
    __shared__ __align__(16) float WgT[E_][D_];   // 32 KB

    int tid = threadIdx.x;
    int wave = tid >> 6, lane = tid & 63;
    int token0 = blockIdx.x * 8;
    int t = token0 >> 12;                 // 8 consecutive tokens share t
    const float* wgb = Wg + (size_t)t * D_ * E_;

#pragma unroll
    for (int r = 0; r < 8; ++r) {
        int f = r * 1024 + tid * 4;       // flat Wg index; (d=f>>3, e=f&7)
        float4 v = *(const float4*)(wgb + f);
        WgT[f & 7][f >> 3]             = v.x;
        WgT[(f + 1) & 7][(f + 1) >> 3] = v.y;
        WgT[(f + 2) & 7][(f + 2) >> 3] = v.z;
        WgT[(f + 3) & 7][(f + 3) >> 3] = v.w;
    }
    __syncthreads();

#pragma unroll
    for (int tl = 0; tl < 2; ++tl) {
        int token = token0 + wave * 2 + tl;
        const float* xrow = x + (size_t)token * D_;

        float4 xv[4];
#pragma unroll
        for (int c = 0; c < 4; ++c)
            xv[c] = *(const float4*)(xrow + c * 256 + lane * 4);

        float acc[E_] = {0.f, 0.f, 0.f, 0.f, 0.f, 0.f, 0.f, 0.f};
#pragma unroll
        for (int c = 0; c < 4; ++c) {
            int d0 = c * 256 + lane * 4;
            unsigned lo = f2bf(xv[c].x) | ((unsigned)f2bf(xv[c].y) << 16);
            unsigned hi = f2bf(xv[c].z) | ((unsigned)f2bf(xv[c].w) << 16);
            *(uint2*)(&xb[(size_t)token * D_ + d0]) = make_uint2(lo, hi);
#pragma unroll
            for (int e = 0; e < E_; ++e) {
                float4 w = *(const float4*)(&WgT[e][d0]);
                acc[e] += xv[c].x * w.x + xv[c].y * w.y + xv[c].z * w.z + xv[c].w * w.w;
            }
        }
#pragma unroll
        for (int off = 1; off < 64; off <<= 1) {
#pragma unroll
            for (int e = 0; e < E_; ++e) acc[e] += __shfl_xor(acc[e], off, 64);
        }

        if (lane == 0) {
            // top-2, lowest-index-first on ties (matches jax.lax.top_k)
            float best = acc[0]; int bi = 0;
#pragma unroll
            for (int e = 1; e < E_; ++e) if (acc[e] > best) { best = acc[e]; bi = e; }
            float sec = -INFINITY; int si = 0;
#pragma unroll
            for (int e = 0; e < E_; ++e) if (e != bi && acc[e] > sec) { sec = acc[e]; si = e; }
            float s = best + sec + 1e-9f;
            route[token] = bi | (si << 8);
            gpair[token] = make_float2(best / s, sec / s);
        }
    }
}

// ---------------------------------------------------------------------------
// Kernel 1b: deterministic stream compaction, one block per (t,e) group.
// 1024 threads: 4 serial chunk iterations instead of 16.
// toklist entry = n | (slot<<16); slot = 0 if e is token's primary expert.
// ---------------------------------------------------------------------------
__global__ __launch_bounds__(1024) void build_lists(
    const int* __restrict__ route, const float2* __restrict__ gpair,
    int* __restrict__ toklist, float* __restrict__ gatelist,
    int* __restrict__ counts)
{
    int g = blockIdx.x;              // t*8 + e
    int t = g >> 3, e = g & 7;
    int tid = threadIdx.x;
    int wave = tid >> 6, lane = tid & 63;

    __shared__ int waveSum[16];
    __shared__ int base;
    if (tid == 0) base = 0;

    for (int c = 0; c < N_; c += 1024) {
        int n = c + tid;
        int r = route[t * N_ + n];
        int e0 = r & 255, e1 = (r >> 8) & 255;
        bool sel = (e0 == e) || (e1 == e);
        unsigned long long b = __ballot(sel);
        int pre  = __popcll(b & ((1ull << lane) - 1ull));
        if (lane == 0) waveSum[wave] = __popcll(b);
        __syncthreads();
        int woff = 0, total = 0;
#pragma unroll
        for (int w = 0; w < 16; ++w) {
            int s = waveSum[w];
            total += s;
            woff += (w < wave) ? s : 0;
        }
        if (sel) {
            int p = base + woff + pre;
            int slot = (e0 == e) ? 0 : 1;
            toklist[g * N_ + p] = n | (slot << 16);
            float2 gp = gpair[t * N_ + n];
            gatelist[g * N_ + p] = (e0 == e) ? gp.x : gp.y;
        }
        __syncthreads();
        if (tid == 0) base += total;
    }
    __syncthreads();
    if (tid == 0) counts[g] = base;
}

// ---------------------------------------------------------------------------
// Kernel 2: We fp32 [e][d][o] -> bf16 packed [(e*8+o/128)*128 + o%128][d].
// ---------------------------------------------------------------------------
__global__ __launch_bounds__(256) void pack_kernel(
    const float* __restrict__ We, unsigned short* __restrict__ Wbp)
{
    __shared__ __align__(16) unsigned short P[64 * 136];

    int b = blockIdx.x;
    int e  = b >> 7;
    int oy = (b & 127) >> 3;   // 0..15
    int dz = b & 7;            // 0..7
    int o0 = oy * 64, d0 = dz * 128;
    int tid = threadIdx.x;

#pragma unroll
    for (int r = 0; r < 32; ++r) {
        int lin = r * 256 + tid;
        int dd = lin >> 6, oo = lin & 63;
        P[oo * 136 + dd] = f2bf(We[((size_t)(e * D_ + d0 + dd)) * O_ + o0 + oo]);
    }
    __syncthreads();

#pragma unroll
    for (int w = 0; w < 4; ++w) {
        int ci = w * 256 + tid;      // 1024 16B-chunks
        int oo = ci >> 4, dc = ci & 15;
        uint4 v = *(const uint4*)&P[oo * 136 + dc * 8];
        int o = o0 + oo;
        int ot = o >> 7, nn = o & 127;
        unsigned short* dst =
            Wbp + ((size_t)((e * 8 + ot) * 128 + nn)) * D_ + d0 + dc * 8;
        *(uint4*)dst = v;
    }
}

// ---------------------------------------------------------------------------
// Kernel 3: grouped GEMM, round 11.
// r10 post-mortem: 128x256 tile -> 284 regs/wave -> 1 wave/SIMD -> 12.5%
// MfmaUtil (occupancy collapse).  REVERTED to r9 footprint (64 AGPR, 128x128).
// r9 post-mortem: per-K-step wall 1274cyc vs 310cyc resident MFMA demand;
// the __syncthreads vmcnt(0) drain exposes full L2/HBM latency every step.
// Fix (T3+T4): TRIPLE-buffered LDS, ONE raw s_barrier per step, counted
// s_waitcnt vmcnt(4) -- tiles t+1,t+2 stay in flight across barriers, never
// drained to 0 in the main loop (m218: counted-vs-drain0 = +38..73%).
// Safety: distance-2 buffer reuse => the tile-t barrier proves all reads of
// the stage target finished (no second barrier needed); asm memory-clobber +
// sched_barrier(0) pin LDS ops to their phase (ds_read hoist above s_barrier
// would read rows other waves haven't landed).  s_setprio(1) around MFMA
// cluster (T5 pays once the schedule has wave role-split, m218b/m224).
// LDS 49.2KB -> 3 blocks/CU; regs ~80+64 -> 3 waves/SIMD.
//  - quarter-phase-balanced swizzle kept (0 conflicts, r9-verified).
//  - mt-SLOWEST dispatch order + xcd = lin%8 kept.  1-D grid 4096.
// ---------------------------------------------------------------------------
__global__ __launch_bounds__(256) void moe_gemm(
    const unsigned short* __restrict__ xb,   // [T*N][D] bf16
    const unsigned short* __restrict__ Wbp,  // [(e*8+ot)*128+n][D] bf16
    const int* __restrict__ toklist, const float* __restrict__ gatelist,
    const int* __restrict__ counts, float* __restrict__ out)
{
    int lin = blockIdx.x;            // 0..4095
    int mt  = lin >> 7;              // slowest: real tiles (mt < ~9) first
    int u   = lin & 127;
    int xcd = u & 7;                 // == lin % 8 == hw XCD round-robin
    int v   = u >> 3;                // 0..15
    int g   = 2 * xcd + (v >> 3);    // xcd owns groups {2x, 2x+1}
    int ot  = v & 7;
    int t   = g >> 3;

    int cnt = counts[g];
    int m0 = mt * BM;
    if (m0 >= cnt) return;

    __shared__ __align__(16) unsigned short As[3][BM * BK];  // 24 KB
    __shared__ __align__(16) unsigned short Bs[3][BN * BK];  // 24 KB
    __shared__ int   tokS[BM];
    __shared__ float gateS[BM];

    int tid = threadIdx.x;
    if (tid < BM) {
        int r = m0 + tid;
        tokS[tid]  = (r < cnt) ? toklist[g * N_ + r]  : -1;
        gateS[tid] = (r < cnt) ? gatelist[g * N_ + r] : 0.f;
    }
    __syncthreads();   // drains vmcnt+lgkm: queues empty entering the pipeline

    int wave = tid >> 6, lane = tid & 63;
    // staging: wave w stages 16-row chunks 2w, 2w+1 of A and B.
    // lane l -> row (l>>2) of chunk, LDS granule (l&3); source granule
    // sg = (l&3)^((l>>3)&3), so LDS pos p of row r holds granule p^((r>>1)&3)
    // (chunk bases are multiples of 16 -> (r>>1)&3 == (lr>>1)&3).
    int lr = lane >> 2;
    int sg = (lane & 3) ^ ((lane >> 3) & 3);
    int c0 = wave * 2, c1 = c0 + 1;
    int ar0 = c0 * 16 + lr, ar1 = c1 * 16 + lr;
    int tok0 = max(tokS[ar0], 0) & 0xFFFF;   // junk rows masked in epilogue
    int tok1 = max(tokS[ar1], 0) & 0xFFFF;
    const unsigned short* ag0 = xb + ((size_t)(t * N_ + tok0)) * D_ + sg * 8;
    const unsigned short* ag1 = xb + ((size_t)(t * N_ + tok1)) * D_ + sg * 8;
    const unsigned short* wb  = Wbp + ((size_t)((g & 7) * 8 + ot) * 128) * D_;
    const unsigned short* bg0 = wb + (size_t)ar0 * D_ + sg * 8;
    const unsigned short* bg1 = wb + (size_t)ar1 * D_ + sg * 8;

    int fr = lane & 15, q = lane >> 4;
    int wm = (wave & 1) * 64, wn = (wave >> 1) * 64;
    int fp = (q ^ ((fr >> 1) & 3)) * 8;      // read-side swizzled granule

    f32x4 acc[4][4];
#pragma unroll
    for (int mi = 0; mi < 4; ++mi)
#pragma unroll
        for (int ni = 0; ni < 4; ++ni) acc[mi][ni] = (f32x4){0.f, 0.f, 0.f, 0.f};

#define STAGE(BUF, KOFF)                                                       \
    {                                                                          \
        gld16(ag0 + (KOFF), &As[BUF][c0 * 512]);                               \
        gld16(ag1 + (KOFF), &As[BUF][c1 * 512]);                               \
        gld16(bg0 + (KOFF), &Bs[BUF][c0 * 512]);                               \
        gld16(bg1 + (KOFF), &Bs[BUF][c1 * 512]);                               \
    }

    // prologue: tiles 0,1 in flight (8 loads/wave)
    STAGE(0, 0)
    STAGE(1, BK)

    // Per step t (reading buf t%3, vmcnt immediate VM, optional stage of
    // tile t+2 at KOFF into buf (t+2)%3 == the buffer read at t-1):
#define KSTEP(CUR, SPARE, KOFF, VM, DOSTAGE)                                   \
    {                                                                          \
        asm volatile("s_waitcnt vmcnt(" #VM ")" ::: "memory");                 \
        __builtin_amdgcn_s_barrier();                                          \
        asm volatile("" ::: "memory");          /* IR fence: no LDS hoist */   \
        __builtin_amdgcn_sched_barrier(0);      /* MIR fence */                \
        if (DOSTAGE) STAGE(SPARE, KOFF)                                        \
        short8 af[4], bf[4];                                                   \
        _Pragma("unroll") for (int mi = 0; mi < 4; ++mi)                       \
            af[mi] = *(const short8*)(&As[CUR][(wm + mi * 16 + fr) * BK + fp]);\
        _Pragma("unroll") for (int ni = 0; ni < 4; ++ni)                       \
            bf[ni] = *(const short8*)(&Bs[CUR][(wn + ni * 16 + fr) * BK + fp]);\
        __builtin_amdgcn_s_setprio(1);                                         \
        _Pragma("unroll") for (int mi = 0; mi < 4; ++mi)                       \
            _Pragma("unroll") for (int ni = 0; ni < 4; ++ni)                   \
                acc[mi][ni] = __builtin_amdgcn_mfma_f32_16x16x32_bf16(         \
                    af[mi], bf[ni], acc[mi][ni], 0, 0, 0);                     \
        __builtin_amdgcn_s_setprio(0);                                         \
    }

    // main: t = 0..29 (stage tiles 2..31), unrolled x3 for static buf indices
    for (int it = 0; it < 30; it += 3) {
        KSTEP(0, 2, (size_t)(it + 2) * BK, 4, 1)
        KSTEP(1, 0, (size_t)(it + 3) * BK, 4, 1)
        KSTEP(2, 1, (size_t)(it + 4) * BK, 4, 1)
    }
    // tail: t=30 (tile31's 4 loads still in flight), t=31 (drain to 0)
    KSTEP(0, 2, 0, 4, 0)
    KSTEP(1, 2, 0, 0, 0)
#undef KSTEP
#undef STAGE

    // epilogue: C/D layout col = lane&15, row = q*4 + reg  [m89/m91]
    float* outb = out + (size_t)t * N_ * O_;
    int ncol = ot * 128 + wn + fr;
#pragma unroll
    for (int mi = 0; mi < 4; ++mi) {
#pragma unroll
        for (int r = 0; r < 4; ++r) {
            int ml = wm + mi * 16 + q * 4 + r;
            int ent = tokS[ml];
            if (ent >= 0) {
                int tok  = ent & 0xFFFF;
                int slot = ent >> 16;
                float gate = gateS[ml];
#pragma unroll
                for (int ni = 0; ni < 4; ++ni) {
                    unsigned short* p =
                        (unsigned short*)(outb + (size_t)tok * O_ + ncol + ni * 16);
                    p[slot] = f2bf(gate * acc[mi][ni][r]);
                }
            }
        }
    }
}

// ---------------------------------------------------------------------------
// Kernel 4: combine the two bf16 slot halves of each out word into fp32.
// ---------------------------------------------------------------------------
__global__ __launch_bounds__(256) void combine_kernel(float* __restrict__ out)
{
    size_t i = ((size_t)blockIdx.x * 256 + threadIdx.x) * 4;
    unsigned* po = (unsigned*)out;
    uint4 v = *(uint4*)(po + i);
    float4 r;
    union { unsigned u; float f; } a, b;
#define CMB(comp, src) a.u = (src) << 16; b.u = (src) & 0xFFFF0000u; comp = a.f + b.f
    CMB(r.x, v.x); CMB(r.y, v.y); CMB(r.z, v.z); CMB(r.w, v.w);
#undef CMB
    *(float4*)(out + i) = r;
}

// ---------------------------------------------------------------------------
extern "C" void kernel_launch(void* const* d_in, const int* in_sizes, int n_in,
                              void* d_out, int out_size, void* d_ws, size_t ws_size,
                              hipStream_t stream)
{
    const float* x  = (const float*)d_in[0];
    const float* Wg = (const float*)d_in[1];
    const float* We = (const float*)d_in[2];
    float* out = (float*)d_out;

    char* ws = (char*)d_ws;
    unsigned short* xb   = (unsigned short*)(ws);               // 16,777,216 B
    unsigned short* Wbp  = (unsigned short*)(ws + 16777216);    // 16,777,216 B
    int*   toklist       = (int*)  (ws + 33554432);             //    262,144 B
    float* gatelist      = (float*)(ws + 33816576);             //    262,144 B
    int*   counts        = (int*)  (ws + 34078720);             //        256 B
    int*   route         = (int*)  (ws + 34078976);             //     32,768 B
    float2* gpair        = (float2*)(ws + 34111744);            //     65,536 B

    gate_kernel<<<(T_ * N_) / 8, 256, 0, stream>>>(x, Wg, xb, route, gpair);
    build_lists<<<T_ * E_, 1024, 0, stream>>>(route, gpair, toklist, gatelist, counts);
    pack_kernel<<<E_ * (O_ / 64) * (D_ / 128), 256, 0, stream>>>(We, Wbp);
    moe_gemm<<<(N_ / BM) * 8 * (T_ * E_), 256, 0, stream>>>(
        xb, Wbp, toklist, gatelist, counts, out);
    combine_kernel<<<((size_t)T_ * N_ * O_) / (256 * 4), 256, 0, stream>>>(out);
}

// Round 4
// 200.519 us; speedup vs baseline: 1.1709x; 1.0244x over previous
//
#include <hip/hip_runtime.h>
#include <hip/hip_bf16.h>
#include <stdint.h>

#define T_ 2
#define N_ 4096
#define D_ 1024
#define E_ 8
#define O_ 1024

#define BM 128
#define BN 128
#define BK 32   // 64-B LDS rows

typedef __attribute__((ext_vector_type(8))) short short8;
typedef __attribute__((ext_vector_type(4))) float f32x4;

#define AS1 __attribute__((address_space(1)))
#define AS3 __attribute__((address_space(3)))

// async global->LDS, 16B per lane; LDS dest = base + lane*16 (wave-uniform base)
__device__ inline void gld16(const unsigned short* g, unsigned short* l) {
    __builtin_amdgcn_global_load_lds((const AS1 unsigned int*)g,
                                     (AS3 unsigned int*)l, 16, 0, 0);
}

__device__ inline unsigned short f2bf(float f) {
    union { float f; unsigned u; } v; v.f = f;
    unsigned r = v.u + 0x7fff + ((v.u >> 16) & 1);  // RNE
    return (unsigned short)(r >> 16);
}

// ---------------------------------------------------------------------------
// Kernel 1 (fused): blocks 0..1023 = gating + x->bf16 (8 tokens/block);
// blocks 1024..2047 = We fp32 [e][d][o] -> bf16 packed
// [(e*8+o/128)*128+o%128][d].  The two halves touch disjoint data; fusing
// them into one launch runs pack's ~48MB of traffic CONCURRENTLY with gate
// instead of serialized behind it (saves ~8-10us + one launch).
// ---------------------------------------------------------------------------
__global__ __launch_bounds__(256) void prep_kernel(
    const float* __restrict__ x, const float* __restrict__ Wg,
    const float* __restrict__ We,
    unsigned short* __restrict__ xb, unsigned short* __restrict__ Wbp,
    int* __restrict__ route, float2* __restrict__ gpair)
{
    __shared__ __align__(16) char smem[E_ * D_ * 4];   // 32 KB (gate); pack uses 17.4 KB
    int tid = threadIdx.x;

    if (blockIdx.x < 1024) {
        // ---- gate half ----
        float (*WgT)[D_] = (float(*)[D_])smem;
        int wave = tid >> 6, lane = tid & 63;
        int token0 = blockIdx.x * 8;
        int t = token0 >> 12;                 // 8 consecutive tokens share t
        const float* wgb = Wg + (size_t)t * D_ * E_;

#pragma unroll
        for (int r = 0; r < 8; ++r) {
            int f = r * 1024 + tid * 4;       // flat Wg index; (d=f>>3, e=f&7)
            float4 v = *(const float4*)(wgb + f);
            WgT[f & 7][f >> 3]             = v.x;
            WgT[(f + 1) & 7][(f + 1) >> 3] = v.y;
            WgT[(f + 2) & 7][(f + 2) >> 3] = v.z;
            WgT[(f + 3) & 7][(f + 3) >> 3] = v.w;
        }
        __syncthreads();

#pragma unroll
        for (int tl = 0; tl < 2; ++tl) {
            int token = token0 + wave * 2 + tl;
            const float* xrow = x + (size_t)token * D_;

            float4 xv[4];
#pragma unroll
            for (int c = 0; c < 4; ++c)
                xv[c] = *(const float4*)(xrow + c * 256 + lane * 4);

            float acc[E_] = {0.f, 0.f, 0.f, 0.f, 0.f, 0.f, 0.f, 0.f};
#pragma unroll
            for (int c = 0; c < 4; ++c) {
                int d0 = c * 256 + lane * 4;
                unsigned lo = f2bf(xv[c].x) | ((unsigned)f2bf(xv[c].y) << 16);
                unsigned hi = f2bf(xv[c].z) | ((unsigned)f2bf(xv[c].w) << 16);
                *(uint2*)(&xb[(size_t)token * D_ + d0]) = make_uint2(lo, hi);
#pragma unroll
                for (int e = 0; e < E_; ++e) {
                    float4 w = *(const float4*)(&WgT[e][d0]);
                    acc[e] += xv[c].x * w.x + xv[c].y * w.y + xv[c].z * w.z + xv[c].w * w.w;
                }
            }
#pragma unroll
            for (int off = 1; off < 64; off <<= 1) {
#pragma unroll
                for (int e = 0; e < E_; ++e) acc[e] += __shfl_xor(acc[e], off, 64);
            }

            if (lane == 0) {
                // top-2, lowest-index-first on ties (matches jax.lax.top_k)
                float best = acc[0]; int bi = 0;
#pragma unroll
                for (int e = 1; e < E_; ++e) if (acc[e] > best) { best = acc[e]; bi = e; }
                float sec = -INFINITY; int si = 0;
#pragma unroll
                for (int e = 0; e < E_; ++e) if (e != bi && acc[e] > sec) { sec = acc[e]; si = e; }
                float s = best + sec + 1e-9f;
                route[token] = bi | (si << 8);
                gpair[token] = make_float2(best / s, sec / s);
            }
        }
    } else {
        // ---- pack half ----
        unsigned short* P = (unsigned short*)smem;   // [64*136] = 17.4 KB

        int b = blockIdx.x - 1024;
        int e  = b >> 7;
        int oy = (b & 127) >> 3;   // 0..15
        int dz = b & 7;            // 0..7
        int o0 = oy * 64, d0 = dz * 128;

#pragma unroll
        for (int r = 0; r < 32; ++r) {
            int lin = r * 256 + tid;
            int dd = lin >> 6, oo = lin & 63;
            P[oo * 136 + dd] = f2bf(We[((size_t)(e * D_ + d0 + dd)) * O_ + o0 + oo]);
        }
        __syncthreads();

#pragma unroll
        for (int w = 0; w < 4; ++w) {
            int ci = w * 256 + tid;      // 1024 16B-chunks
            int oo = ci >> 4, dc = ci & 15;
            uint4 v = *(const uint4*)&P[oo * 136 + dc * 8];
            int o = o0 + oo;
            int ot = o >> 7, nn = o & 127;
            unsigned short* dst =
                Wbp + ((size_t)((e * 8 + ot) * 128 + nn)) * D_ + d0 + dc * 8;
            *(uint4*)dst = v;
        }
    }
}

// ---------------------------------------------------------------------------
// Kernel 1b: deterministic stream compaction, one block per (t,e) group.
// 1024 threads: 4 serial chunk iterations instead of 16.
// toklist entry = n | (slot<<16); slot = 0 if e is token's primary expert.
// ---------------------------------------------------------------------------
__global__ __launch_bounds__(1024) void build_lists(
    const int* __restrict__ route, const float2* __restrict__ gpair,
    int* __restrict__ toklist, float* __restrict__ gatelist,
    int* __restrict__ counts)
{
    int g = blockIdx.x;              // t*8 + e
    int t = g >> 3, e = g & 7;
    int tid = threadIdx.x;
    int wave = tid >> 6, lane = tid & 63;

    __shared__ int waveSum[16];
    __shared__ int base;
    if (tid == 0) base = 0;

    for (int c = 0; c < N_; c += 1024) {
        int n = c + tid;
        int r = route[t * N_ + n];
        int e0 = r & 255, e1 = (r >> 8) & 255;
        bool sel = (e0 == e) || (e1 == e);
        unsigned long long b = __ballot(sel);
        int pre  = __popcll(b & ((1ull << lane) - 1ull));
        if (lane == 0) waveSum[wave] = __popcll(b);
        __syncthreads();
        int woff = 0, total = 0;
#pragma unroll
        for (int w = 0; w < 16; ++w) {
            int s = waveSum[w];
            total += s;
            woff += (w < wave) ? s : 0;
        }
        if (sel) {
            int p = base + woff + pre;
            int slot = (e0 == e) ? 0 : 1;
            toklist[g * N_ + p] = n | (slot << 16);
            float2 gp = gpair[t * N_ + n];
            gatelist[g * N_ + p] = (e0 == e) ? gp.x : gp.y;
        }
        __syncthreads();
        if (tid == 0) base += total;
    }
    __syncthreads();
    if (tid == 0) counts[g] = base;
}

// ---------------------------------------------------------------------------
// Kernel 3: grouped GEMM, round 12 = r11 structure MINUS order-pinning.
// r11 post-mortem: counted-vmcnt 3-buf pipeline regressed 68->82us, but two
// confounds: (a) LDS 49KB -> 3 blocks/CU (occupancy 22->16%), (b)
// sched_barrier(0)+setprio+full fences per step = m141's order-pinning
// failure (874->510 TF there; MfmaUtil FELL 20.5->17 here).  This round
// isolates (b): identical 3-buf counted-vmcnt schedule, pins deleted.
// Correctness-minimal fences kept: asm waitcnt w/ memory clobber before the
// raw s_barrier, one IR-level memory fence after it (stops LDS ops crossing
// the barrier; lets the MIR scheduler interleave freely otherwise).
// If this lands <68us the structure wins; if ~75+ the 3-buf occupancy cost
// dominates -> revert to 2-buf next round.
// ---------------------------------------------------------------------------
__global__ __launch_bounds__(256) void moe_gemm(
    const unsigned short* __restrict__ xb,   // [T*N][D] bf16
    const unsigned short* __restrict__ Wbp,  // [(e*8+ot)*128+n][D] bf16
    const int* __restrict__ toklist, const float* __restrict__ gatelist,
    const int* __restrict__ counts, float* __restrict__ out)
{
    int lin = blockIdx.x;            // 0..4095
    int mt  = lin >> 7;              // slowest: real tiles (mt < ~9) first
    int u   = lin & 127;
    int xcd = u & 7;                 // == lin % 8 == hw XCD round-robin
    int v   = u >> 3;                // 0..15
    int g   = 2 * xcd + (v >> 3);    // xcd owns groups {2x, 2x+1}
    int ot  = v & 7;
    int t   = g >> 3;

    int cnt = counts[g];
    int m0 = mt * BM;
    if (m0 >= cnt) return;

    __shared__ __align__(16) unsigned short As[3][BM * BK];  // 24 KB
    __shared__ __align__(16) unsigned short Bs[3][BN * BK];  // 24 KB
    __shared__ int   tokS[BM];
    __shared__ float gateS[BM];

    int tid = threadIdx.x;
    if (tid < BM) {
        int r = m0 + tid;
        tokS[tid]  = (r < cnt) ? toklist[g * N_ + r]  : -1;
        gateS[tid] = (r < cnt) ? gatelist[g * N_ + r] : 0.f;
    }
    __syncthreads();   // drains vmcnt+lgkm: queues empty entering the pipeline

    int wave = tid >> 6, lane = tid & 63;
    // staging: wave w stages 16-row chunks 2w, 2w+1 of A and B.
    // lane l -> row (l>>2) of chunk, LDS granule (l&3); source granule
    // sg = (l&3)^((l>>3)&3), so LDS pos p of row r holds granule p^((r>>1)&3)
    // (chunk bases are multiples of 16 -> (r>>1)&3 == (lr>>1)&3).
    int lr = lane >> 2;
    int sg = (lane & 3) ^ ((lane >> 3) & 3);
    int c0 = wave * 2, c1 = c0 + 1;
    int ar0 = c0 * 16 + lr, ar1 = c1 * 16 + lr;
    int tok0 = max(tokS[ar0], 0) & 0xFFFF;   // junk rows masked in epilogue
    int tok1 = max(tokS[ar1], 0) & 0xFFFF;
    const unsigned short* ag0 = xb + ((size_t)(t * N_ + tok0)) * D_ + sg * 8;
    const unsigned short* ag1 = xb + ((size_t)(t * N_ + tok1)) * D_ + sg * 8;
    const unsigned short* wb  = Wbp + ((size_t)((g & 7) * 8 + ot) * 128) * D_;
    const unsigned short* bg0 = wb + (size_t)ar0 * D_ + sg * 8;
    const unsigned short* bg1 = wb + (size_t)ar1 * D_ + sg * 8;

    int fr = lane & 15, q = lane >> 4;
    int wm = (wave & 1) * 64, wn = (wave >> 1) * 64;
    int fp = (q ^ ((fr >> 1) & 3)) * 8;      // read-side swizzled granule

    f32x4 acc[4][4];
#pragma unroll
    for (int mi = 0; mi < 4; ++mi)
#pragma unroll
        for (int ni = 0; ni < 4; ++ni) acc[mi][ni] = (f32x4){0.f, 0.f, 0.f, 0.f};

#define STAGE(BUF, KOFF)                                                       \
    {                                                                          \
        gld16(ag0 + (KOFF), &As[BUF][c0 * 512]);                               \
        gld16(ag1 + (KOFF), &As[BUF][c1 * 512]);                               \
        gld16(bg0 + (KOFF), &Bs[BUF][c0 * 512]);                               \
        gld16(bg1 + (KOFF), &Bs[BUF][c1 * 512]);                               \
    }

    // prologue: tiles 0,1 in flight (8 loads/wave)
    STAGE(0, 0)
    STAGE(1, BK)

    // Per step t (reading buf t%3, vmcnt immediate VM, optional stage of
    // tile t+2 at KOFF into buf (t+2)%3 == the buffer read at t-1; the
    // barrier proves all waves finished those reads):
#define KSTEP(CUR, SPARE, KOFF, VM, DOSTAGE)                                   \
    {                                                                          \
        asm volatile("s_waitcnt vmcnt(" #VM ")" ::: "memory");                 \
        __builtin_amdgcn_s_barrier();                                          \
        asm volatile("" ::: "memory");  /* IR fence: no LDS ops cross bar */   \
        if (DOSTAGE) STAGE(SPARE, KOFF)                                        \
        short8 af[4], bf[4];                                                   \
        _Pragma("unroll") for (int mi = 0; mi < 4; ++mi)                       \
            af[mi] = *(const short8*)(&As[CUR][(wm + mi * 16 + fr) * BK + fp]);\
        _Pragma("unroll") for (int ni = 0; ni < 4; ++ni)                       \
            bf[ni] = *(const short8*)(&Bs[CUR][(wn + ni * 16 + fr) * BK + fp]);\
        _Pragma("unroll") for (int mi = 0; mi < 4; ++mi)                       \
            _Pragma("unroll") for (int ni = 0; ni < 4; ++ni)                   \
                acc[mi][ni] = __builtin_amdgcn_mfma_f32_16x16x32_bf16(         \
                    af[mi], bf[ni], acc[mi][ni], 0, 0, 0);                     \
    }

    // main: t = 0..29 (stage tiles 2..31), unrolled x3 for static buf indices
    for (int it = 0; it < 30; it += 3) {
        KSTEP(0, 2, (size_t)(it + 2) * BK, 4, 1)
        KSTEP(1, 0, (size_t)(it + 3) * BK, 4, 1)
        KSTEP(2, 1, (size_t)(it + 4) * BK, 4, 1)
    }
    // tail: t=30 (tile31's 4 loads still in flight), t=31 (drain to 0)
    KSTEP(0, 2, 0, 4, 0)
    KSTEP(1, 2, 0, 0, 0)
#undef KSTEP
#undef STAGE

    // epilogue: C/D layout col = lane&15, row = q*4 + reg  [m89/m91]
    float* outb = out + (size_t)t * N_ * O_;
    int ncol = ot * 128 + wn + fr;
#pragma unroll
    for (int mi = 0; mi < 4; ++mi) {
#pragma unroll
        for (int r = 0; r < 4; ++r) {
            int ml = wm + mi * 16 + q * 4 + r;
            int ent = tokS[ml];
            if (ent >= 0) {
                int tok  = ent & 0xFFFF;
                int slot = ent >> 16;
                float gate = gateS[ml];
#pragma unroll
                for (int ni = 0; ni < 4; ++ni) {
                    unsigned short* p =
                        (unsigned short*)(outb + (size_t)tok * O_ + ncol + ni * 16);
                    p[slot] = f2bf(gate * acc[mi][ni][r]);
                }
            }
        }
    }
}

// ---------------------------------------------------------------------------
// Kernel 4: combine the two bf16 slot halves of each out word into fp32.
// ---------------------------------------------------------------------------
__global__ __launch_bounds__(256) void combine_kernel(float* __restrict__ out)
{
    size_t i = ((size_t)blockIdx.x * 256 + threadIdx.x) * 4;
    unsigned* po = (unsigned*)out;
    uint4 v = *(uint4*)(po + i);
    float4 r;
    union { unsigned u; float f; } a, b;
#define CMB(comp, src) a.u = (src) << 16; b.u = (src) & 0xFFFF0000u; comp = a.f + b.f
    CMB(r.x, v.x); CMB(r.y, v.y); CMB(r.z, v.z); CMB(r.w, v.w);
#undef CMB
    *(float4*)(out + i) = r;
}

// ---------------------------------------------------------------------------
extern "C" void kernel_launch(void* const* d_in, const int* in_sizes, int n_in,
                              void* d_out, int out_size, void* d_ws, size_t ws_size,
                              hipStream_t stream)
{
    const float* x  = (const float*)d_in[0];
    const float* Wg = (const float*)d_in[1];
    const float* We = (const float*)d_in[2];
    float* out = (float*)d_out;

    char* ws = (char*)d_ws;
    unsigned short* xb   = (unsigned short*)(ws);               // 16,777,216 B
    unsigned short* Wbp  = (unsigned short*)(ws + 16777216);    // 16,777,216 B
    int*   toklist       = (int*)  (ws + 33554432);             //    262,144 B
    float* gatelist      = (float*)(ws + 33816576);             //    262,144 B
    int*   counts        = (int*)  (ws + 34078720);             //        256 B
    int*   route         = (int*)  (ws + 34078976);             //     32,768 B
    float2* gpair        = (float2*)(ws + 34111744);            //     65,536 B

    prep_kernel<<<2048, 256, 0, stream>>>(x, Wg, We, xb, Wbp, route, gpair);
    build_lists<<<T_ * E_, 1024, 0, stream>>>(route, gpair, toklist, gatelist, counts);
    moe_gemm<<<(N_ / BM) * 8 * (T_ * E_), 256, 0, stream>>>(
        xb, Wbp, toklist, gatelist, counts, out);
    combine_kernel<<<((size_t)T_ * N_ * O_) / (256 * 4), 256, 0, stream>>>(out);
}

// Round 5
// 183.527 us; speedup vs baseline: 1.2794x; 1.0926x over previous
//
#include <hip/hip_runtime.h>
#include <hip/hip_bf16.h>
#include <stdint.h>

#define T_ 2
#define N_ 4096
#define D_ 1024
#define E_ 8
#define O_ 1024

#define BM 128
#define BN 128
#define BK 32   // 64-B LDS rows

typedef __attribute__((ext_vector_type(8))) short short8;
typedef __attribute__((ext_vector_type(4))) float f32x4;

#define AS1 __attribute__((address_space(1)))
#define AS3 __attribute__((address_space(3)))

// async global->LDS, 16B per lane; LDS dest = base + lane*16 (wave-uniform base)
__device__ inline void gld16(const unsigned short* g, unsigned short* l) {
    __builtin_amdgcn_global_load_lds((const AS1 unsigned int*)g,
                                     (AS3 unsigned int*)l, 16, 0, 0);
}

__device__ inline unsigned short f2bf(float f) {
    union { float f; unsigned u; } v; v.f = f;
    unsigned r = v.u + 0x7fff + ((v.u >> 16) & 1);  // RNE
    return (unsigned short)(r >> 16);
}

// ---------------------------------------------------------------------------
// Kernel 1 (fused): blocks 0..1023 = gating + x->bf16 (8 tokens/block);
// blocks 1024..2047 = We fp32 [e][d][o] -> bf16 packed
// [(e*8+o/128)*128+o%128][d].  Disjoint data; fused so pack's ~48MB of
// traffic runs concurrently with gate.
// ---------------------------------------------------------------------------
__global__ __launch_bounds__(256) void prep_kernel(
    const float* __restrict__ x, const float* __restrict__ Wg,
    const float* __restrict__ We,
    unsigned short* __restrict__ xb, unsigned short* __restrict__ Wbp,
    int* __restrict__ route, float2* __restrict__ gpair)
{
    __shared__ __align__(16) char smem[E_ * D_ * 4];   // 32 KB (gate); pack uses 17.4 KB
    int tid = threadIdx.x;

    if (blockIdx.x < 1024) {
        // ---- gate half ----
        float (*WgT)[D_] = (float(*)[D_])smem;
        int wave = tid >> 6, lane = tid & 63;
        int token0 = blockIdx.x * 8;
        int t = token0 >> 12;                 // 8 consecutive tokens share t
        const float* wgb = Wg + (size_t)t * D_ * E_;

#pragma unroll
        for (int r = 0; r < 8; ++r) {
            int f = r * 1024 + tid * 4;       // flat Wg index; (d=f>>3, e=f&7)
            float4 v = *(const float4*)(wgb + f);
            WgT[f & 7][f >> 3]             = v.x;
            WgT[(f + 1) & 7][(f + 1) >> 3] = v.y;
            WgT[(f + 2) & 7][(f + 2) >> 3] = v.z;
            WgT[(f + 3) & 7][(f + 3) >> 3] = v.w;
        }
        __syncthreads();

#pragma unroll
        for (int tl = 0; tl < 2; ++tl) {
            int token = token0 + wave * 2 + tl;
            const float* xrow = x + (size_t)token * D_;

            float4 xv[4];
#pragma unroll
            for (int c = 0; c < 4; ++c)
                xv[c] = *(const float4*)(xrow + c * 256 + lane * 4);

            float acc[E_] = {0.f, 0.f, 0.f, 0.f, 0.f, 0.f, 0.f, 0.f};
#pragma unroll
            for (int c = 0; c < 4; ++c) {
                int d0 = c * 256 + lane * 4;
                unsigned lo = f2bf(xv[c].x) | ((unsigned)f2bf(xv[c].y) << 16);
                unsigned hi = f2bf(xv[c].z) | ((unsigned)f2bf(xv[c].w) << 16);
                *(uint2*)(&xb[(size_t)token * D_ + d0]) = make_uint2(lo, hi);
#pragma unroll
                for (int e = 0; e < E_; ++e) {
                    float4 w = *(const float4*)(&WgT[e][d0]);
                    acc[e] += xv[c].x * w.x + xv[c].y * w.y + xv[c].z * w.z + xv[c].w * w.w;
                }
            }
#pragma unroll
            for (int off = 1; off < 64; off <<= 1) {
#pragma unroll
                for (int e = 0; e < E_; ++e) acc[e] += __shfl_xor(acc[e], off, 64);
            }

            if (lane == 0) {
                // top-2, lowest-index-first on ties (matches jax.lax.top_k)
                float best = acc[0]; int bi = 0;
#pragma unroll
                for (int e = 1; e < E_; ++e) if (acc[e] > best) { best = acc[e]; bi = e; }
                float sec = -INFINITY; int si = 0;
#pragma unroll
                for (int e = 0; e < E_; ++e) if (e != bi && acc[e] > sec) { sec = acc[e]; si = e; }
                float s = best + sec + 1e-9f;
                route[token] = bi | (si << 8);
                gpair[token] = make_float2(best / s, sec / s);
            }
        }
    } else {
        // ---- pack half ----
        unsigned short* P = (unsigned short*)smem;   // [64*136] = 17.4 KB

        int b = blockIdx.x - 1024;
        int e  = b >> 7;
        int oy = (b & 127) >> 3;   // 0..15
        int dz = b & 7;            // 0..7
        int o0 = oy * 64, d0 = dz * 128;

#pragma unroll
        for (int r = 0; r < 32; ++r) {
            int lin = r * 256 + tid;
            int dd = lin >> 6, oo = lin & 63;
            P[oo * 136 + dd] = f2bf(We[((size_t)(e * D_ + d0 + dd)) * O_ + o0 + oo]);
        }
        __syncthreads();

#pragma unroll
        for (int w = 0; w < 4; ++w) {
            int ci = w * 256 + tid;      // 1024 16B-chunks
            int oo = ci >> 4, dc = ci & 15;
            uint4 v = *(const uint4*)&P[oo * 136 + dc * 8];
            int o = o0 + oo;
            int ot = o >> 7, nn = o & 127;
            unsigned short* dst =
                Wbp + ((size_t)((e * 8 + ot) * 128 + nn)) * D_ + d0 + dc * 8;
            *(uint4*)dst = v;
        }
    }
}

// ---------------------------------------------------------------------------
// Kernel 1b: deterministic stream compaction, one block per (t,e) group.
// 1024 threads: 4 serial chunk iterations instead of 16.
// toklist entry = n | (slot<<16); slot = 0 if e is token's primary expert.
// ---------------------------------------------------------------------------
__global__ __launch_bounds__(1024) void build_lists(
    const int* __restrict__ route, const float2* __restrict__ gpair,
    int* __restrict__ toklist, float* __restrict__ gatelist,
    int* __restrict__ counts)
{
    int g = blockIdx.x;              // t*8 + e
    int t = g >> 3, e = g & 7;
    int tid = threadIdx.x;
    int wave = tid >> 6, lane = tid & 63;

    __shared__ int waveSum[16];
    __shared__ int base;
    if (tid == 0) base = 0;

    for (int c = 0; c < N_; c += 1024) {
        int n = c + tid;
        int r = route[t * N_ + n];
        int e0 = r & 255, e1 = (r >> 8) & 255;
        bool sel = (e0 == e) || (e1 == e);
        unsigned long long b = __ballot(sel);
        int pre  = __popcll(b & ((1ull << lane) - 1ull));
        if (lane == 0) waveSum[wave] = __popcll(b);
        __syncthreads();
        int woff = 0, total = 0;
#pragma unroll
        for (int w = 0; w < 16; ++w) {
            int s = waveSum[w];
            total += s;
            woff += (w < wave) ? s : 0;
        }
        if (sel) {
            int p = base + woff + pre;
            int slot = (e0 == e) ? 0 : 1;
            toklist[g * N_ + p] = n | (slot << 16);
            float2 gp = gpair[t * N_ + n];
            gatelist[g * N_ + p] = (e0 == e) ? gp.x : gp.y;
        }
        __syncthreads();
        if (tid == 0) base += total;
    }
    __syncthreads();
    if (tid == 0) counts[g] = base;
}

// ---------------------------------------------------------------------------
// Kernel 3: grouped GEMM, round 13.
// r11/r12 post-mortem: counted-vmcnt 3-buf == r9-structure scaled by
// occupancy -> the pins and the vmcnt scheme were both ~neutral; occupancy
// is THE lever.  And occupancy is REGISTER-capped, not LDS-capped: r9 ran
// 80 VGPR + 64 acc AGPR = 144 unified regs > 128 -> 8 waves/CU (m69
// halving), exactly the observed 22%.  Fix: same proven r9 2-buf loop +
// 128x128 tile, decomposed over 8 WAVES (512 thr).  Per wave: 64x32 out =
// 32 AGPR acc, 1 A-chunk + 1 B-chunk staged (2 gld16), 6 ds_read_b128,
// 8 MFMA/step.  ~70 VGPR + 32 AGPR <= 128 -> 16 waves/CU (2 blocks x 8),
// enforced by __launch_bounds__(512,4).  Doubled TLP, halved per-wave
// chain; staging traffic & tile shape unchanged.
//  - quarter-phase swizzle kept: row bases are multiples of 16 so
//    (r>>1)&3 stays lane-local (verified: 16k+fr >>1 = 8k+(fr>>1)).
//  - mt-SLOWEST dispatch order + xcd = lin%8 kept.  1-D grid 4096.
// ---------------------------------------------------------------------------
__global__ __launch_bounds__(512, 4) void moe_gemm(
    const unsigned short* __restrict__ xb,   // [T*N][D] bf16
    const unsigned short* __restrict__ Wbp,  // [(e*8+ot)*128+n][D] bf16
    const int* __restrict__ toklist, const float* __restrict__ gatelist,
    const int* __restrict__ counts, float* __restrict__ out)
{
    int lin = blockIdx.x;            // 0..4095
    int mt  = lin >> 7;              // slowest: real tiles (mt < ~9) first
    int u   = lin & 127;
    int xcd = u & 7;                 // == lin % 8 == hw XCD round-robin
    int v   = u >> 3;                // 0..15
    int g   = 2 * xcd + (v >> 3);    // xcd owns groups {2x, 2x+1}
    int ot  = v & 7;
    int t   = g >> 3;

    int cnt = counts[g];
    int m0 = mt * BM;
    if (m0 >= cnt) return;

    __shared__ __align__(16) unsigned short As[2][BM * BK];  // 16 KB
    __shared__ __align__(16) unsigned short Bs[2][BN * BK];  // 16 KB
    __shared__ int   tokS[BM];
    __shared__ float gateS[BM];

    int tid = threadIdx.x;
    if (tid < BM) {
        int r = m0 + tid;
        tokS[tid]  = (r < cnt) ? toklist[g * N_ + r]  : -1;
        gateS[tid] = (r < cnt) ? gatelist[g * N_ + r] : 0.f;
    }
    __syncthreads();

    int wave = tid >> 6, lane = tid & 63;   // 8 waves
    // staging: wave w stages 16-row chunk w of A and of B (1 KB each).
    // lane l -> row (l>>2) of chunk, LDS granule (l&3); source granule
    // sg = (l&3)^((l>>3)&3), so LDS pos p of row r holds granule p^((r>>1)&3)
    // (chunk base 16w: (16w+lr)>>1 = 8w+(lr>>1), 8w%4==0).
    int lr = lane >> 2;
    int sg = (lane & 3) ^ ((lane >> 3) & 3);
    int ar = wave * 16 + lr;
    int tok = max(tokS[ar], 0) & 0xFFFF;     // junk rows masked in epilogue
    const unsigned short* ag = xb + ((size_t)(t * N_ + tok)) * D_ + sg * 8;
    const unsigned short* wb = Wbp + ((size_t)((g & 7) * 8 + ot) * 128) * D_;
    const unsigned short* bg = wb + (size_t)ar * D_ + sg * 8;

    int fr = lane & 15, q = lane >> 4;
    int wm = (wave & 1) * 64;                // 2 x 4 wave grid: 64 x 32 / wave
    int wn = (wave >> 1) * 32;
    int fp = (q ^ ((fr >> 1) & 3)) * 8;      // read-side swizzled granule

    f32x4 acc[4][2];
#pragma unroll
    for (int mi = 0; mi < 4; ++mi)
#pragma unroll
        for (int ni = 0; ni < 2; ++ni) acc[mi][ni] = (f32x4){0.f, 0.f, 0.f, 0.f};

    // prologue: stage K-tile 0 into buffer 0
    gld16(ag, &As[0][wave * 512]);
    gld16(bg, &Bs[0][wave * 512]);

#define KSTEP(CUR, NXT, IT)                                                    \
    {                                                                          \
        __syncthreads(); /* drains vmcnt (tile IT landed) + NXT reads done */  \
        int k1 = ((IT) + 1) * BK;                                              \
        if (k1 < D_) {                                                         \
            gld16(ag + k1, &As[NXT][wave * 512]);                              \
            gld16(bg + k1, &Bs[NXT][wave * 512]);                              \
        }                                                                      \
        short8 af[4], bf[2];                                                   \
        _Pragma("unroll") for (int mi = 0; mi < 4; ++mi)                       \
            af[mi] = *(const short8*)(&As[CUR][(wm + mi * 16 + fr) * BK + fp]);\
        _Pragma("unroll") for (int ni = 0; ni < 2; ++ni)                       \
            bf[ni] = *(const short8*)(&Bs[CUR][(wn + ni * 16 + fr) * BK + fp]);\
        _Pragma("unroll") for (int mi = 0; mi < 4; ++mi)                       \
            _Pragma("unroll") for (int ni = 0; ni < 2; ++ni)                   \
                acc[mi][ni] = __builtin_amdgcn_mfma_f32_16x16x32_bf16(         \
                    af[mi], bf[ni], acc[mi][ni], 0, 0, 0);                     \
    }

    for (int it = 0; it < D_ / BK; it += 2) {
        KSTEP(0, 1, it)
        KSTEP(1, 0, it + 1)
    }
#undef KSTEP

    // epilogue: C/D layout col = lane&15, row = q*4 + reg  [m89/m91]
    float* outb = out + (size_t)t * N_ * O_;
    int ncol = ot * 128 + wn + fr;
#pragma unroll
    for (int mi = 0; mi < 4; ++mi) {
#pragma unroll
        for (int r = 0; r < 4; ++r) {
            int ml = wm + mi * 16 + q * 4 + r;
            int ent = tokS[ml];
            if (ent >= 0) {
                int tokk = ent & 0xFFFF;
                int slot = ent >> 16;
                float gate = gateS[ml];
#pragma unroll
                for (int ni = 0; ni < 2; ++ni) {
                    unsigned short* p =
                        (unsigned short*)(outb + (size_t)tokk * O_ + ncol + ni * 16);
                    p[slot] = f2bf(gate * acc[mi][ni][r]);
                }
            }
        }
    }
}

// ---------------------------------------------------------------------------
// Kernel 4: combine the two bf16 slot halves of each out word into fp32.
// ---------------------------------------------------------------------------
__global__ __launch_bounds__(256) void combine_kernel(float* __restrict__ out)
{
    size_t i = ((size_t)blockIdx.x * 256 + threadIdx.x) * 4;
    unsigned* po = (unsigned*)out;
    uint4 v = *(uint4*)(po + i);
    float4 r;
    union { unsigned u; float f; } a, b;
#define CMB(comp, src) a.u = (src) << 16; b.u = (src) & 0xFFFF0000u; comp = a.f + b.f
    CMB(r.x, v.x); CMB(r.y, v.y); CMB(r.z, v.z); CMB(r.w, v.w);
#undef CMB
    *(float4*)(out + i) = r;
}

// ---------------------------------------------------------------------------
extern "C" void kernel_launch(void* const* d_in, const int* in_sizes, int n_in,
                              void* d_out, int out_size, void* d_ws, size_t ws_size,
                              hipStream_t stream)
{
    const float* x  = (const float*)d_in[0];
    const float* Wg = (const float*)d_in[1];
    const float* We = (const float*)d_in[2];
    float* out = (float*)d_out;

    char* ws = (char*)d_ws;
    unsigned short* xb   = (unsigned short*)(ws);               // 16,777,216 B
    unsigned short* Wbp  = (unsigned short*)(ws + 16777216);    // 16,777,216 B
    int*   toklist       = (int*)  (ws + 33554432);             //    262,144 B
    float* gatelist      = (float*)(ws + 33816576);             //    262,144 B
    int*   counts        = (int*)  (ws + 34078720);             //        256 B
    int*   route         = (int*)  (ws + 34078976);             //     32,768 B
    float2* gpair        = (float2*)(ws + 34111744);            //     65,536 B

    prep_kernel<<<2048, 256, 0, stream>>>(x, Wg, We, xb, Wbp, route, gpair);
    build_lists<<<T_ * E_, 1024, 0, stream>>>(route, gpair, toklist, gatelist, counts);
    moe_gemm<<<(N_ / BM) * 8 * (T_ * E_), 512, 0, stream>>>(
        xb, Wbp, toklist, gatelist, counts, out);
    combine_kernel<<<((size_t)T_ * N_ * O_) / (256 * 4), 256, 0, stream>>>(out);
}